// Round 11
// baseline (70.343 us; speedup 1.0000x reference)
//
#include <hip/hip_runtime.h>
#include <hip/hip_fp16.h>

#define BB_ 8
#define VV_ 5023
#define FF_ 9976
#define HH_ 512
#define K_ADJ 32

static constexpr long long OUT_UV   = 0;                                   // uvcoords_images (B,3,H,H)
static constexpr long long OUT_POS  = OUT_UV   + (long long)BB_*3*HH_*HH_; // pos_mask        (B,1,H,H)
static constexpr long long OUT_GRID = OUT_POS  + (long long)BB_*HH_*HH_;   // grid            (B,H,H,2)
static constexpr long long OUT_N    = OUT_GRID + (long long)BB_*HH_*HH_*2; // normals         (B,V,3)
static constexpr long long OUT_NIMG = OUT_N    + (long long)BB_*VV_*3;     // normal_images   (B,3,H,H)
static constexpr long long OUT_TN   = OUT_NIMG + (long long)BB_*3*HH_*HH_; // t_normals       (B,V,3)

typedef float __attribute__((ext_vector_type(4))) f4;
typedef int   __attribute__((ext_vector_type(4))) i4;

__device__ inline float pack_h2(float a, float b) {
    union { float f; __half2 h; } u;
    u.h = __halves2half2(__float2half_rn(a), __float2half_rn(b));
    return u.f;
}
__device__ inline float2 unpack_h2(float w) {
    union { float f; __half2 h; } u; u.f = w;
    return __half22float2(u.h);
}

// ---------------------------------------------------------------------------
// K1: BOTH meshes' face normals per (b,f) thread; b==0 threads also build the
// fixed-capacity adjacency table (int atomics) AND the batch-independent
// uvrec table (9 pre-scaled uv halves, 32 B/face -> 319 KB, L2-hot).
// All three reference scatter-adds equal cross(v1-v0, v2-v0); z+10 applied
// before differencing (matches ref rounding).
// ---------------------------------------------------------------------------
__global__ __launch_bounds__(256) void facenorm2_k(const float* __restrict__ verts,
                                                   const float* __restrict__ tverts,
                                                   const int*   __restrict__ faces,
                                                   const float* __restrict__ uvc,
                                                   float4* __restrict__ fnorm,
                                                   float4* __restrict__ uvrec,
                                                   int*    __restrict__ cnt,
                                                   int*    __restrict__ adj) {
    int t = blockIdx.x * blockDim.x + threadIdx.x;
    if (t >= BB_ * FF_) return;
    int b = t / FF_;
    int f = t - b * FF_;

    int i0 = faces[f*3+0], i1 = faces[f*3+1], i2 = faces[f*3+2];

    {
        const float* vb = verts + (long long)b * VV_ * 3;
        float v0x = vb[i0*3+0], v0y = vb[i0*3+1], v0z = vb[i0*3+2];
        float v1x = vb[i1*3+0], v1y = vb[i1*3+1], v1z = vb[i1*3+2];
        float v2x = vb[i2*3+0], v2y = vb[i2*3+1], v2z = vb[i2*3+2];
        float ax = v1x - v0x, ay = v1y - v0y, az = v1z - v0z;
        float bx = v2x - v0x, by = v2y - v0y, bz = v2z - v0z;
        fnorm[(long long)(b*2+0) * FF_ + f] =
            make_float4(ay*bz - az*by, az*bx - ax*bz, ax*by - ay*bx, 0.f);
    }
    {
        const float* vb = tverts + (long long)b * VV_ * 3;
        float v0x = vb[i0*3+0], v0y = vb[i0*3+1], v0z = vb[i0*3+2] + 10.0f;
        float v1x = vb[i1*3+0], v1y = vb[i1*3+1], v1z = vb[i1*3+2] + 10.0f;
        float v2x = vb[i2*3+0], v2y = vb[i2*3+1], v2z = vb[i2*3+2] + 10.0f;
        float ax = v1x - v0x, ay = v1y - v0y, az = v1z - v0z;
        float bx = v2x - v0x, by = v2y - v0y, bz = v2z - v0z;
        fnorm[(long long)(b*2+1) * FF_ + f] =
            make_float4(ay*bz - az*by, az*bx - ax*bz, ax*by - ay*bx, 0.f);
    }

    if (b == 0) {
        int s0 = atomicAdd(&cnt[i0], 1); if (s0 < K_ADJ) adj[i0*K_ADJ + s0] = f;
        int s1 = atomicAdd(&cnt[i1], 1); if (s1 < K_ADJ) adj[i1*K_ADJ + s1] = f;
        int s2 = atomicAdd(&cnt[i2], 1); if (s2 < K_ADJ) adj[i2*K_ADJ + s2] = f;

        const float* u = uvc + (long long)f * 9;
        float r0 = u[0]*0.5f+0.5f, r1 = u[1]*0.5f+0.5f, r2 = u[2]*0.5f+0.5f;
        float r3 = u[3]*0.5f+0.5f, r4 = u[4]*0.5f+0.5f, r5 = u[5]*0.5f+0.5f;
        float r6 = u[6]*0.5f+0.5f, r7 = u[7]*0.5f+0.5f, r8 = u[8]*0.5f+0.5f;
        uvrec[(long long)f*2+0] = make_float4(pack_h2(r0,r1), pack_h2(r2,r3),
                                              pack_h2(r4,r5), pack_h2(r6,r7));
        uvrec[(long long)f*2+1] = make_float4(pack_h2(r8,0.f), 0.f, 0.f, 0.f);
    }
}

// ---------------------------------------------------------------------------
// K2: gather BOTH meshes per (b,v) thread. Sums adjacent face normals from
// the L2-resident fnorm buffer, normalizes, writes normals / t_normals
// outputs AND packed nbuf[b,v] = (nx, ny, nz, tnz).
// ---------------------------------------------------------------------------
__global__ __launch_bounds__(256) void gather2_k(const int* __restrict__ cnt,
                                                 const int* __restrict__ adj,
                                                 const float4* __restrict__ fnorm,
                                                 float* __restrict__ outN,
                                                 float* __restrict__ outTN,
                                                 float4* __restrict__ nbuf) {
    int t = blockIdx.x * blockDim.x + threadIdx.x;
    if (t >= BB_ * VV_) return;
    int b = t / VV_;
    int v = t - b * VV_;
    int deg = min(cnt[v], K_ADJ);
    const float4* f0 = fnorm + (long long)(b*2+0) * FF_;
    const float4* f1 = fnorm + (long long)(b*2+1) * FF_;
    float x0 = 0.f, y0 = 0.f, z0 = 0.f;
    float x1 = 0.f, y1 = 0.f, z1 = 0.f;
    for (int j = 0; j < deg; ++j) {
        int f = adj[v*K_ADJ + j];
        float4 a = f0[f];
        x0 += a.x; y0 += a.y; z0 += a.z;
        float4 c = f1[f];
        x1 += c.x; y1 += c.y; z1 += c.z;
    }
    float nx, ny, nz, tnz;
    {
        float inv = 1.0f / fmaxf(sqrtf(x0*x0 + y0*y0 + z0*z0), 1e-6f);
        nx = x0 * inv; ny = y0 * inv; nz = z0 * inv;
        float* o = outN + (long long)t * 3;
        o[0] = nx; o[1] = ny; o[2] = nz;
    }
    {
        float inv = 1.0f / fmaxf(sqrtf(x1*x1 + y1*y1 + z1*z1), 1e-6f);
        tnz = z1 * inv;
        float* o = outTN + (long long)t * 3;
        o[0] = x1 * inv; o[1] = y1 * inv; o[2] = tnz;
    }
    nbuf[t] = make_float4(nx, ny, nz, tnz);
}

// ---------------------------------------------------------------------------
// K3: 32-B nrec per (b,f) from 3 aligned float4 nbuf reads:
//   q0 = (tnz_a, tnz_b, tnz_c, pack(ncz, 0))   -- tnz fp32: hard threshold
//   q1 = (pack(nax,nay), pack(naz,nbx), pack(nby,nbz), pack(ncx,ncy))
// nrec total 2.55 MB -> L2-resident per XCD alongside streams.
// ---------------------------------------------------------------------------
__global__ __launch_bounds__(256) void build_nrec(const int*    __restrict__ faces,
                                                  const float4* __restrict__ nbuf,
                                                  float4* __restrict__ nrec) {
    int t = blockIdx.x * blockDim.x + threadIdx.x;
    if (t >= BB_ * FF_) return;
    int b = t / FF_;
    int f = t - b * FF_;
    int ia = faces[f*3+0], ib = faces[f*3+1], ic = faces[f*3+2];

    const float4* nb = nbuf + (long long)b * VV_;
    float4 A = nb[ia], Bv = nb[ib], C = nb[ic];

    nrec[(long long)t*2+0] = make_float4(A.w, Bv.w, C.w, pack_h2(C.z, 0.f));
    nrec[(long long)t*2+1] = make_float4(pack_h2(A.x,A.y), pack_h2(A.z,Bv.x),
                                         pack_h2(Bv.y,Bv.z), pack_h2(C.x,C.y));
}

// ---------------------------------------------------------------------------
// Per-pixel shade: 2 float4 loads from the hot uvrec line + 2 float4 loads
// from one nrec line; miss pixels issue zero gather traffic.
// (Layout identical to the verified round-3 raster3.)
// ---------------------------------------------------------------------------
__device__ __forceinline__ void shade(int pf, float w0, float w1, float w2,
                                      const float4* __restrict__ uvrec,
                                      const float4* __restrict__ nrec,
                                      float& uv0, float& uv1, float& uv2,
                                      float& n0, float& n1, float& n2, float& pm) {
    uv0 = uv1 = uv2 = n0 = n1 = n2 = pm = 0.0f;
    if (pf < 0) return;
    int bb = pf / FF_;
    int ff = pf - bb * FF_;

    float4 U0 = uvrec[(long long)ff*2+0];
    float  U8 = ((const float*)uvrec)[(long long)ff*8+4];
    float4 A  = nrec[(long long)pf*2+0];
    float4 Bq = nrec[(long long)pf*2+1];

    float2 u01 = unpack_h2(U0.x), u23 = unpack_h2(U0.y);
    float2 u45 = unpack_h2(U0.z), u67 = unpack_h2(U0.w);
    float2 u8p = unpack_h2(U8);
    float2 m01 = unpack_h2(Bq.x), m23 = unpack_h2(Bq.y);
    float2 m45 = unpack_h2(Bq.z), m67 = unpack_h2(Bq.w);
    float2 m8p = unpack_h2(A.w);

    uv0 = w0*u01.x + w1*u23.y + w2*u67.x;
    uv1 = w0*u01.y + w1*u45.x + w2*u67.y;
    uv2 = w0*u23.x + w1*u45.y + w2*u8p.x;
    n0  = w0*m01.x + w1*m23.y + w2*m67.x;
    n1  = w0*m01.y + w1*m45.x + w2*m67.y;
    n2  = w0*m23.x + w1*m45.y + w2*m8p.x;
    float tnz = w0*A.x + w1*A.y + w2*A.z;   // fp32: hard threshold
    pm = (tnz < -0.05f) ? 1.0f : 0.0f;
}

// ---------------------------------------------------------------------------
// K4: raster, 4 consecutive pixels/thread (proven sweet spot). NT loads for
// read-once streams, NT stores for write-once outputs.
// ---------------------------------------------------------------------------
__global__ __launch_bounds__(256) void raster7(const i4* __restrict__ p2f4,
                                               const f4* __restrict__ bary4,
                                               const float4* __restrict__ uvrec,
                                               const float4* __restrict__ nrec,
                                               float* __restrict__ out) {
    int t = blockIdx.x * blockDim.x + threadIdx.x;
    const int NQ = BB_ * HH_ * HH_ / 4;
    if (t >= NQ) return;
    int pix0 = t << 2;
    int b    = pix0 >> 18;               // H*H = 2^18
    int yx0  = pix0 & (HH_*HH_ - 1);

    i4 pf = __builtin_nontemporal_load(p2f4 + t);
    f4 B0 = __builtin_nontemporal_load(bary4 + (long long)t*3 + 0);
    f4 B1 = __builtin_nontemporal_load(bary4 + (long long)t*3 + 1);
    f4 B2 = __builtin_nontemporal_load(bary4 + (long long)t*3 + 2);

    float uv0a, uv1a, uv2a, n0a, n1a, n2a, pma;
    float uv0b, uv1b, uv2b, n0b, n1b, n2b, pmb;
    float uv0c, uv1c, uv2c, n0c, n1c, n2c, pmc;
    float uv0d, uv1d, uv2d, n0d, n1d, n2d, pmd;

    shade(pf.x, B0.x, B0.y, B0.z, uvrec, nrec, uv0a, uv1a, uv2a, n0a, n1a, n2a, pma);
    shade(pf.y, B0.w, B1.x, B1.y, uvrec, nrec, uv0b, uv1b, uv2b, n0b, n1b, n2b, pmb);
    shade(pf.z, B1.z, B1.w, B2.x, uvrec, nrec, uv0c, uv1c, uv2c, n0c, n1c, n2c, pmc);
    shade(pf.w, B2.y, B2.z, B2.w, uvrec, nrec, uv0d, uv1d, uv2d, n0d, n1d, n2d, pmd);

    const long long HW = (long long)HH_ * HH_;
    f4 vuv0 = {uv0a, uv0b, uv0c, uv0d};
    f4 vuv1 = {uv1a, uv1b, uv1c, uv1d};
    f4 vuv2 = {uv2a, uv2b, uv2c, uv2d};
    f4 vpos = {pma,  pmb,  pmc,  pmd};
    f4 vg0  = {uv0a, uv1a, uv0b, uv1b};
    f4 vg1  = {uv0c, uv1c, uv0d, uv1d};
    f4 vn0  = {n0a, n0b, n0c, n0d};
    f4 vn1  = {n1a, n1b, n1c, n1d};
    f4 vn2  = {n2a, n2b, n2c, n2d};

    __builtin_nontemporal_store(vuv0, (f4*)(out + OUT_UV  + ((long long)(b*3+0))*HW + yx0));
    __builtin_nontemporal_store(vuv1, (f4*)(out + OUT_UV  + ((long long)(b*3+1))*HW + yx0));
    __builtin_nontemporal_store(vuv2, (f4*)(out + OUT_UV  + ((long long)(b*3+2))*HW + yx0));
    __builtin_nontemporal_store(vpos, (f4*)(out + OUT_POS + (long long)b*HW + yx0));
    float* gbase = out + OUT_GRID + ((long long)b*HW + yx0)*2;
    __builtin_nontemporal_store(vg0, (f4*)(gbase + 0));
    __builtin_nontemporal_store(vg1, (f4*)(gbase + 4));
    __builtin_nontemporal_store(vn0, (f4*)(out + OUT_NIMG + ((long long)(b*3+0))*HW + yx0));
    __builtin_nontemporal_store(vn1, (f4*)(out + OUT_NIMG + ((long long)(b*3+1))*HW + yx0));
    __builtin_nontemporal_store(vn2, (f4*)(out + OUT_NIMG + ((long long)(b*3+2))*HW + yx0));
}

extern "C" void kernel_launch(void* const* d_in, const int* in_sizes, int n_in,
                              void* d_out, int out_size, void* d_ws, size_t ws_size,
                              hipStream_t stream) {
    const float* vertices  = (const float*)d_in[0];
    const float* tvertices = (const float*)d_in[1];
    const float* face_uvc  = (const float*)d_in[3];
    const float* bary      = (const float*)d_in[4];
    const int*   faces     = (const int*)d_in[5];
    const int*   p2f       = (const int*)d_in[6];

    float* out = (float*)d_out;

    // ws layout (16B-aligned first): uvrec | nrec | fnorm | nbuf | cnt | adj
    float4* uvrec = (float4*)d_ws;                               // F*2 float4
    float4* nrec  = uvrec + (size_t)FF_ * 2;                     // B*F*2 float4
    float4* fnorm = nrec + (size_t)BB_ * FF_ * 2;                // B*2*F float4
    float4* nbuf  = fnorm + (size_t)BB_ * 2 * FF_;               // B*V float4
    int*    cnt   = (int*)(nbuf + (size_t)BB_ * VV_);            // V
    int*    adj   = cnt + VV_;                                   // V*K_ADJ

    hipMemsetAsync(cnt, 0, (size_t)VV_ * sizeof(int), stream);

    {
        int n = BB_ * FF_;
        facenorm2_k<<<(n + 255) / 256, 256, 0, stream>>>(vertices, tvertices, faces,
                                                         face_uvc, fnorm, uvrec, cnt, adj);
    }
    {
        int n = BB_ * VV_;
        gather2_k<<<(n + 255) / 256, 256, 0, stream>>>(cnt, adj, fnorm,
                                                       out + OUT_N, out + OUT_TN, nbuf);
    }
    {
        int n = BB_ * FF_;
        build_nrec<<<(n + 255) / 256, 256, 0, stream>>>(faces, nbuf, nrec);
    }
    {
        int nq = BB_ * HH_ * HH_ / 4;
        raster7<<<(nq + 255) / 256, 256, 0, stream>>>((const i4*)p2f, (const f4*)bary,
                                                      uvrec, nrec, out);
    }
}

// Round 12
// 65.620 us; speedup vs baseline: 1.0720x; 1.0720x over previous
//
#include <hip/hip_runtime.h>
#include <hip/hip_fp16.h>

#define BB_ 8
#define VV_ 5023
#define FF_ 9976
#define HH_ 512
#define K_ADJ 32

static constexpr long long OUT_UV   = 0;                                   // uvcoords_images (B,3,H,H)
static constexpr long long OUT_POS  = OUT_UV   + (long long)BB_*3*HH_*HH_; // pos_mask        (B,1,H,H)
static constexpr long long OUT_GRID = OUT_POS  + (long long)BB_*HH_*HH_;   // grid            (B,H,H,2)
static constexpr long long OUT_N    = OUT_GRID + (long long)BB_*HH_*HH_*2; // normals         (B,V,3)
static constexpr long long OUT_NIMG = OUT_N    + (long long)BB_*VV_*3;     // normal_images   (B,3,H,H)
static constexpr long long OUT_TN   = OUT_NIMG + (long long)BB_*3*HH_*HH_; // t_normals       (B,V,3)

typedef float __attribute__((ext_vector_type(4))) f4;
typedef int   __attribute__((ext_vector_type(4))) i4;

__device__ inline float pack_h2(float a, float b) {
    union { float f; __half2 h; } u;
    u.h = __halves2half2(__float2half_rn(a), __float2half_rn(b));
    return u.f;
}
__device__ inline float2 unpack_h2(float w) {
    union { float f; __half2 h; } u; u.f = w;
    return __half22float2(u.h);
}

// ---------------------------------------------------------------------------
// K1: one face normal per (b, mesh, f) -- 160K threads, 64-thread blocks
// (~10 blocks/CU: TLP hides the 9 scattered vertex-load latencies).
// (b==0,m==0) threads also build adjacency (int atomics) + uvrec (L2-hot).
// All three reference scatter-adds equal cross(v1-v0, v2-v0); z+10 applied
// before differencing (matches ref rounding).
// ---------------------------------------------------------------------------
__global__ __launch_bounds__(64) void facenorm3_k(const float* __restrict__ verts,
                                                  const float* __restrict__ tverts,
                                                  const int*   __restrict__ faces,
                                                  const float* __restrict__ uvc,
                                                  float4* __restrict__ fnorm,
                                                  float4* __restrict__ uvrec,
                                                  int*    __restrict__ cnt,
                                                  int*    __restrict__ adj) {
    int t = blockIdx.x * 64 + threadIdx.x;
    if (t >= BB_ * 2 * FF_) return;
    int bm = t / FF_;                 // b*2 + m
    int f  = t - bm * FF_;
    int m  = bm & 1;
    int b  = bm >> 1;

    int i0 = faces[f*3+0], i1 = faces[f*3+1], i2 = faces[f*3+2];

    const float* vb = (m ? tverts : verts) + (long long)b * VV_ * 3;
    const float zoff = m ? 10.0f : 0.0f;
    float v0x = vb[i0*3+0], v0y = vb[i0*3+1], v0z = vb[i0*3+2] + zoff;
    float v1x = vb[i1*3+0], v1y = vb[i1*3+1], v1z = vb[i1*3+2] + zoff;
    float v2x = vb[i2*3+0], v2y = vb[i2*3+1], v2z = vb[i2*3+2] + zoff;
    float ax = v1x - v0x, ay = v1y - v0y, az = v1z - v0z;
    float bx = v2x - v0x, by = v2y - v0y, bz = v2z - v0z;
    fnorm[(long long)t] = make_float4(ay*bz - az*by, az*bx - ax*bz, ax*by - ay*bx, 0.f);

    if (bm == 0) {
        int s0 = atomicAdd(&cnt[i0], 1); if (s0 < K_ADJ) adj[i0*K_ADJ + s0] = f;
        int s1 = atomicAdd(&cnt[i1], 1); if (s1 < K_ADJ) adj[i1*K_ADJ + s1] = f;
        int s2 = atomicAdd(&cnt[i2], 1); if (s2 < K_ADJ) adj[i2*K_ADJ + s2] = f;

        const float* u = uvc + (long long)f * 9;
        float r0 = u[0]*0.5f+0.5f, r1 = u[1]*0.5f+0.5f, r2 = u[2]*0.5f+0.5f;
        float r3 = u[3]*0.5f+0.5f, r4 = u[4]*0.5f+0.5f, r5 = u[5]*0.5f+0.5f;
        float r6 = u[6]*0.5f+0.5f, r7 = u[7]*0.5f+0.5f, r8 = u[8]*0.5f+0.5f;
        uvrec[(long long)f*2+0] = make_float4(pack_h2(r0,r1), pack_h2(r2,r3),
                                              pack_h2(r4,r5), pack_h2(r6,r7));
        uvrec[(long long)f*2+1] = make_float4(pack_h2(r8,0.f), 0.f, 0.f, 0.f);
    }
}

// ---------------------------------------------------------------------------
// K2: gather per (b, mesh, v) -- 80K threads, 64-thread blocks (~5 blocks/CU).
// m==0 writes normals output + nbuf.xyz; m==1 writes t_normals output +
// nbuf.w (=tnz). Disjoint bytes of the same float4 -> no race.
// ---------------------------------------------------------------------------
__global__ __launch_bounds__(64) void gather3_k(const int* __restrict__ cnt,
                                                const int* __restrict__ adj,
                                                const float4* __restrict__ fnorm,
                                                float* __restrict__ outN,
                                                float* __restrict__ outTN,
                                                float4* __restrict__ nbuf) {
    int t = blockIdx.x * 64 + threadIdx.x;
    if (t >= BB_ * 2 * VV_) return;
    int bm = t / VV_;                 // b*2 + m
    int v  = t - bm * VV_;
    int m  = bm & 1;
    int b  = bm >> 1;

    int deg = min(cnt[v], K_ADJ);
    const float4* fb = fnorm + (long long)bm * FF_;
    float x = 0.f, y = 0.f, z = 0.f;
    for (int j = 0; j < deg; ++j) {
        int f = adj[v*K_ADJ + j];
        float4 a = fb[f];
        x += a.x; y += a.y; z += a.z;
    }
    float inv = 1.0f / fmaxf(sqrtf(x*x + y*y + z*z), 1e-6f);
    float nx = x * inv, ny = y * inv, nz = z * inv;

    long long idx = (long long)b * VV_ + v;
    float* nb = (float*)(nbuf + idx);
    if (m == 0) {
        float* o = outN + idx * 3;
        o[0] = nx; o[1] = ny; o[2] = nz;
        nb[0] = nx; nb[1] = ny; nb[2] = nz;
    } else {
        float* o = outTN + idx * 3;
        o[0] = nx; o[1] = ny; o[2] = nz;
        nb[3] = nz;                   // tnz (fp32: hard-threshold path)
    }
}

// ---------------------------------------------------------------------------
// K3: ONE 64-B record per (b,f) from 3 aligned float4 nbuf reads + uvc.
//   q0: tnz0..2 fp32 (hard-threshold path), pack(uv8, ncz)
//   q1: uv0..7 halves (pre-scaled);  q2: nax..ncy halves;  q3: pad.
// ---------------------------------------------------------------------------
__global__ __launch_bounds__(64) void build_rec64(const int*    __restrict__ faces,
                                                  const float*  __restrict__ uvc,
                                                  const float4* __restrict__ nbuf,
                                                  float4* __restrict__ rec) {
    int t = blockIdx.x * 64 + threadIdx.x;
    if (t >= BB_ * FF_) return;
    int b = t / FF_;
    int f = t - b * FF_;
    int ia = faces[f*3+0], ib = faces[f*3+1], ic = faces[f*3+2];

    const float4* nb = nbuf + (long long)b * VV_;
    float4 A = nb[ia], Bv = nb[ib], C = nb[ic];

    const float* u = uvc + (long long)f * 9;
    float r0 = u[0]*0.5f+0.5f, r1 = u[1]*0.5f+0.5f, r2 = u[2]*0.5f+0.5f;
    float r3 = u[3]*0.5f+0.5f, r4 = u[4]*0.5f+0.5f, r5 = u[5]*0.5f+0.5f;
    float r6 = u[6]*0.5f+0.5f, r7 = u[7]*0.5f+0.5f, r8 = u[8]*0.5f+0.5f;

    float4* o = rec + (long long)t * 4;
    o[0] = make_float4(A.w, Bv.w, C.w, pack_h2(r8, C.z));
    o[1] = make_float4(pack_h2(r0,r1), pack_h2(r2,r3), pack_h2(r4,r5), pack_h2(r6,r7));
    o[2] = make_float4(pack_h2(A.x,A.y), pack_h2(A.z,Bv.x), pack_h2(Bv.y,Bv.z), pack_h2(C.x,C.y));
}

// ---------------------------------------------------------------------------
// Per-pixel shade: 3 dwordx4 loads from ONE 64-B line; miss pixels issue
// zero gather traffic. (Proven round-10 layout.)
// ---------------------------------------------------------------------------
__device__ __forceinline__ void shade(int pf, float w0, float w1, float w2,
                                      const float4* __restrict__ rec,
                                      float& uv0, float& uv1, float& uv2,
                                      float& n0, float& n1, float& n2, float& pm) {
    uv0 = uv1 = uv2 = n0 = n1 = n2 = pm = 0.0f;
    if (pf < 0) return;
    const float4* R = rec + (long long)pf * 4;
    float4 q0 = R[0], q1 = R[1], q2 = R[2];

    float2 u8c = unpack_h2(q0.w);     // (uv8, ncz)
    float2 u01 = unpack_h2(q1.x), u23 = unpack_h2(q1.y);
    float2 u45 = unpack_h2(q1.z), u67 = unpack_h2(q1.w);
    float2 m01 = unpack_h2(q2.x), m23 = unpack_h2(q2.y);
    float2 m45 = unpack_h2(q2.z), m67 = unpack_h2(q2.w);

    uv0 = w0*u01.x + w1*u23.y + w2*u67.x;
    uv1 = w0*u01.y + w1*u45.x + w2*u67.y;
    uv2 = w0*u23.x + w1*u45.y + w2*u8c.x;
    n0  = w0*m01.x + w1*m23.y + w2*m67.x;
    n1  = w0*m01.y + w1*m45.x + w2*m67.y;
    n2  = w0*m23.x + w1*m45.y + w2*u8c.y;
    float tnz = w0*q0.x + w1*q0.y + w2*q0.z;   // fp32: hard threshold
    pm = (tnz < -0.05f) ? 1.0f : 0.0f;
}

// ---------------------------------------------------------------------------
// K4: raster, 4 consecutive pixels/thread (proven sweet spot). NT loads for
// read-once streams, NT stores for write-once outputs.
// ---------------------------------------------------------------------------
__global__ __launch_bounds__(256) void raster6(const i4* __restrict__ p2f4,
                                               const f4* __restrict__ bary4,
                                               const float4* __restrict__ rec,
                                               float* __restrict__ out) {
    int t = blockIdx.x * blockDim.x + threadIdx.x;
    const int NQ = BB_ * HH_ * HH_ / 4;
    if (t >= NQ) return;
    int pix0 = t << 2;
    int b    = pix0 >> 18;               // H*H = 2^18
    int yx0  = pix0 & (HH_*HH_ - 1);

    i4 pf = __builtin_nontemporal_load(p2f4 + t);
    f4 B0 = __builtin_nontemporal_load(bary4 + (long long)t*3 + 0);
    f4 B1 = __builtin_nontemporal_load(bary4 + (long long)t*3 + 1);
    f4 B2 = __builtin_nontemporal_load(bary4 + (long long)t*3 + 2);

    float uv0a, uv1a, uv2a, n0a, n1a, n2a, pma;
    float uv0b, uv1b, uv2b, n0b, n1b, n2b, pmb;
    float uv0c, uv1c, uv2c, n0c, n1c, n2c, pmc;
    float uv0d, uv1d, uv2d, n0d, n1d, n2d, pmd;

    shade(pf.x, B0.x, B0.y, B0.z, rec, uv0a, uv1a, uv2a, n0a, n1a, n2a, pma);
    shade(pf.y, B0.w, B1.x, B1.y, rec, uv0b, uv1b, uv2b, n0b, n1b, n2b, pmb);
    shade(pf.z, B1.z, B1.w, B2.x, rec, uv0c, uv1c, uv2c, n0c, n1c, n2c, pmc);
    shade(pf.w, B2.y, B2.z, B2.w, rec, uv0d, uv1d, uv2d, n0d, n1d, n2d, pmd);

    const long long HW = (long long)HH_ * HH_;
    f4 vuv0 = {uv0a, uv0b, uv0c, uv0d};
    f4 vuv1 = {uv1a, uv1b, uv1c, uv1d};
    f4 vuv2 = {uv2a, uv2b, uv2c, uv2d};
    f4 vpos = {pma,  pmb,  pmc,  pmd};
    f4 vg0  = {uv0a, uv1a, uv0b, uv1b};
    f4 vg1  = {uv0c, uv1c, uv0d, uv1d};
    f4 vn0  = {n0a, n0b, n0c, n0d};
    f4 vn1  = {n1a, n1b, n1c, n1d};
    f4 vn2  = {n2a, n2b, n2c, n2d};

    __builtin_nontemporal_store(vuv0, (f4*)(out + OUT_UV  + ((long long)(b*3+0))*HW + yx0));
    __builtin_nontemporal_store(vuv1, (f4*)(out + OUT_UV  + ((long long)(b*3+1))*HW + yx0));
    __builtin_nontemporal_store(vuv2, (f4*)(out + OUT_UV  + ((long long)(b*3+2))*HW + yx0));
    __builtin_nontemporal_store(vpos, (f4*)(out + OUT_POS + (long long)b*HW + yx0));
    float* gbase = out + OUT_GRID + ((long long)b*HW + yx0)*2;
    __builtin_nontemporal_store(vg0, (f4*)(gbase + 0));
    __builtin_nontemporal_store(vg1, (f4*)(gbase + 4));
    __builtin_nontemporal_store(vn0, (f4*)(out + OUT_NIMG + ((long long)(b*3+0))*HW + yx0));
    __builtin_nontemporal_store(vn1, (f4*)(out + OUT_NIMG + ((long long)(b*3+1))*HW + yx0));
    __builtin_nontemporal_store(vn2, (f4*)(out + OUT_NIMG + ((long long)(b*3+2))*HW + yx0));
}

extern "C" void kernel_launch(void* const* d_in, const int* in_sizes, int n_in,
                              void* d_out, int out_size, void* d_ws, size_t ws_size,
                              hipStream_t stream) {
    const float* vertices  = (const float*)d_in[0];
    const float* tvertices = (const float*)d_in[1];
    const float* face_uvc  = (const float*)d_in[3];
    const float* bary      = (const float*)d_in[4];
    const int*   faces     = (const int*)d_in[5];
    const int*   p2f       = (const int*)d_in[6];

    float* out = (float*)d_out;

    // ws layout (16B-aligned first): rec | uvrec | fnorm | nbuf | cnt | adj
    float4* rec   = (float4*)d_ws;                               // B*F*4 float4
    float4* uvrec = rec + (size_t)BB_ * FF_ * 4;                 // F*2 float4
    float4* fnorm = uvrec + (size_t)FF_ * 2;                     // B*2*F float4
    float4* nbuf  = fnorm + (size_t)BB_ * 2 * FF_;               // B*V float4
    int*    cnt   = (int*)(nbuf + (size_t)BB_ * VV_);            // V
    int*    adj   = cnt + VV_;                                   // V*K_ADJ

    hipMemsetAsync(cnt, 0, (size_t)VV_ * sizeof(int), stream);

    {
        int n = BB_ * 2 * FF_;
        facenorm3_k<<<(n + 63) / 64, 64, 0, stream>>>(vertices, tvertices, faces,
                                                      face_uvc, fnorm, uvrec, cnt, adj);
    }
    {
        int n = BB_ * 2 * VV_;
        gather3_k<<<(n + 63) / 64, 64, 0, stream>>>(cnt, adj, fnorm,
                                                    out + OUT_N, out + OUT_TN, nbuf);
    }
    {
        int n = BB_ * FF_;
        build_rec64<<<(n + 63) / 64, 64, 0, stream>>>(faces, face_uvc, nbuf, rec);
    }
    {
        int nq = BB_ * HH_ * HH_ / 4;
        raster6<<<(nq + 255) / 256, 256, 0, stream>>>((const i4*)p2f, (const f4*)bary,
                                                      rec, out);
    }
}

// Round 13
// 63.420 us; speedup vs baseline: 1.1092x; 1.0347x over previous
//
#include <hip/hip_runtime.h>
#include <hip/hip_fp16.h>

#define BB_ 8
#define VV_ 5023
#define FF_ 9976
#define HH_ 512
#define K_ADJ 32

static constexpr long long OUT_UV   = 0;                                   // uvcoords_images (B,3,H,H)
static constexpr long long OUT_POS  = OUT_UV   + (long long)BB_*3*HH_*HH_; // pos_mask        (B,1,H,H)
static constexpr long long OUT_GRID = OUT_POS  + (long long)BB_*HH_*HH_;   // grid            (B,H,H,2)
static constexpr long long OUT_N    = OUT_GRID + (long long)BB_*HH_*HH_*2; // normals         (B,V,3)
static constexpr long long OUT_NIMG = OUT_N    + (long long)BB_*VV_*3;     // normal_images   (B,3,H,H)
static constexpr long long OUT_TN   = OUT_NIMG + (long long)BB_*3*HH_*HH_; // t_normals       (B,V,3)

typedef float __attribute__((ext_vector_type(4))) f4;
typedef int   __attribute__((ext_vector_type(4))) i4;

__device__ inline float pack_h2(float a, float b) {
    union { float f; __half2 h; } u;
    u.h = __halves2half2(__float2half_rn(a), __float2half_rn(b));
    return u.f;
}
__device__ inline float2 unpack_h2(float w) {
    union { float f; __half2 h; } u; u.f = w;
    return __half22float2(u.h);
}

// ---------------------------------------------------------------------------
// K1: one face normal per (b, mesh, f) -- 160K threads, 64-thread blocks
// (~10 blocks/CU TLP hides the 9 scattered vertex-load latencies).
// bm==0 threads also build the adjacency table (int atomics; K=32 >> max deg).
// All three reference scatter-adds equal cross(v1-v0, v2-v0); z+10 applied
// before differencing (matches ref rounding).
// ---------------------------------------------------------------------------
__global__ __launch_bounds__(64) void facenorm3_k(const float* __restrict__ verts,
                                                  const float* __restrict__ tverts,
                                                  const int*   __restrict__ faces,
                                                  float4* __restrict__ fnorm,
                                                  int*    __restrict__ cnt,
                                                  int*    __restrict__ adj) {
    int t = blockIdx.x * 64 + threadIdx.x;
    if (t >= BB_ * 2 * FF_) return;
    int bm = t / FF_;                 // b*2 + m
    int f  = t - bm * FF_;
    int m  = bm & 1;
    int b  = bm >> 1;

    int i0 = faces[f*3+0], i1 = faces[f*3+1], i2 = faces[f*3+2];

    const float* vb = (m ? tverts : verts) + (long long)b * VV_ * 3;
    const float zoff = m ? 10.0f : 0.0f;
    float v0x = vb[i0*3+0], v0y = vb[i0*3+1], v0z = vb[i0*3+2] + zoff;
    float v1x = vb[i1*3+0], v1y = vb[i1*3+1], v1z = vb[i1*3+2] + zoff;
    float v2x = vb[i2*3+0], v2y = vb[i2*3+1], v2z = vb[i2*3+2] + zoff;
    float ax = v1x - v0x, ay = v1y - v0y, az = v1z - v0z;
    float bx = v2x - v0x, by = v2y - v0y, bz = v2z - v0z;
    fnorm[(long long)t] = make_float4(ay*bz - az*by, az*bx - ax*bz, ax*by - ay*bx, 0.f);

    if (bm == 0) {
        int s0 = atomicAdd(&cnt[i0], 1); if (s0 < K_ADJ) adj[i0*K_ADJ + s0] = f;
        int s1 = atomicAdd(&cnt[i1], 1); if (s1 < K_ADJ) adj[i1*K_ADJ + s1] = f;
        int s2 = atomicAdd(&cnt[i2], 1); if (s2 < K_ADJ) adj[i2*K_ADJ + s2] = f;
    }
}

// ---------------------------------------------------------------------------
// K2: gather per (b, mesh, v) -- 80K threads, 64-thread blocks (~5 blocks/CU).
// m==0 writes normals output + nbuf.xyz; m==1 writes t_normals output +
// nbuf.w (=tnz). Disjoint bytes of the same float4 -> no race.
// ---------------------------------------------------------------------------
__global__ __launch_bounds__(64) void gather3_k(const int* __restrict__ cnt,
                                                const int* __restrict__ adj,
                                                const float4* __restrict__ fnorm,
                                                float* __restrict__ outN,
                                                float* __restrict__ outTN,
                                                float4* __restrict__ nbuf) {
    int t = blockIdx.x * 64 + threadIdx.x;
    if (t >= BB_ * 2 * VV_) return;
    int bm = t / VV_;                 // b*2 + m
    int v  = t - bm * VV_;
    int m  = bm & 1;
    int b  = bm >> 1;

    int deg = min(cnt[v], K_ADJ);
    const float4* fb = fnorm + (long long)bm * FF_;
    float x = 0.f, y = 0.f, z = 0.f;
    for (int j = 0; j < deg; ++j) {
        int f = adj[v*K_ADJ + j];
        float4 a = fb[f];
        x += a.x; y += a.y; z += a.z;
    }
    float inv = 1.0f / fmaxf(sqrtf(x*x + y*y + z*z), 1e-6f);
    float nx = x * inv, ny = y * inv, nz = z * inv;

    long long idx = (long long)b * VV_ + v;
    float* nb = (float*)(nbuf + idx);
    if (m == 0) {
        float* o = outN + idx * 3;
        o[0] = nx; o[1] = ny; o[2] = nz;
        nb[0] = nx; nb[1] = ny; nb[2] = nz;
    } else {
        float* o = outTN + idx * 3;
        o[0] = nx; o[1] = ny; o[2] = nz;
        nb[3] = nz;                   // tnz (fp32: hard-threshold path)
    }
}

// ---------------------------------------------------------------------------
// K3: ONE 64-B record per (b,f) from 3 aligned float4 nbuf reads + uvc.
//   q0: tnz0..2 fp32 (hard-threshold path), pack(uv8, ncz)
//   q1: uv0..7 halves (pre-scaled);  q2: nax..ncy halves;  q3: pad.
// ---------------------------------------------------------------------------
__global__ __launch_bounds__(64) void build_rec64(const int*    __restrict__ faces,
                                                  const float*  __restrict__ uvc,
                                                  const float4* __restrict__ nbuf,
                                                  float4* __restrict__ rec) {
    int t = blockIdx.x * 64 + threadIdx.x;
    if (t >= BB_ * FF_) return;
    int b = t / FF_;
    int f = t - b * FF_;
    int ia = faces[f*3+0], ib = faces[f*3+1], ic = faces[f*3+2];

    const float4* nb = nbuf + (long long)b * VV_;
    float4 A = nb[ia], Bv = nb[ib], C = nb[ic];

    const float* u = uvc + (long long)f * 9;
    float r0 = u[0]*0.5f+0.5f, r1 = u[1]*0.5f+0.5f, r2 = u[2]*0.5f+0.5f;
    float r3 = u[3]*0.5f+0.5f, r4 = u[4]*0.5f+0.5f, r5 = u[5]*0.5f+0.5f;
    float r6 = u[6]*0.5f+0.5f, r7 = u[7]*0.5f+0.5f, r8 = u[8]*0.5f+0.5f;

    float4* o = rec + (long long)t * 4;
    o[0] = make_float4(A.w, Bv.w, C.w, pack_h2(r8, C.z));
    o[1] = make_float4(pack_h2(r0,r1), pack_h2(r2,r3), pack_h2(r4,r5), pack_h2(r6,r7));
    o[2] = make_float4(pack_h2(A.x,A.y), pack_h2(A.z,Bv.x), pack_h2(Bv.y,Bv.z), pack_h2(C.x,C.y));
}

// ---------------------------------------------------------------------------
// Per-pixel shade: 3 dwordx4 loads from ONE 64-B line; miss pixels issue
// zero gather traffic. (Proven round-10 layout.)
// ---------------------------------------------------------------------------
__device__ __forceinline__ void shade(int pf, float w0, float w1, float w2,
                                      const float4* __restrict__ rec,
                                      float& uv0, float& uv1, float& uv2,
                                      float& n0, float& n1, float& n2, float& pm) {
    uv0 = uv1 = uv2 = n0 = n1 = n2 = pm = 0.0f;
    if (pf < 0) return;
    const float4* R = rec + (long long)pf * 4;
    float4 q0 = R[0], q1 = R[1], q2 = R[2];

    float2 u8c = unpack_h2(q0.w);     // (uv8, ncz)
    float2 u01 = unpack_h2(q1.x), u23 = unpack_h2(q1.y);
    float2 u45 = unpack_h2(q1.z), u67 = unpack_h2(q1.w);
    float2 m01 = unpack_h2(q2.x), m23 = unpack_h2(q2.y);
    float2 m45 = unpack_h2(q2.z), m67 = unpack_h2(q2.w);

    uv0 = w0*u01.x + w1*u23.y + w2*u67.x;
    uv1 = w0*u01.y + w1*u45.x + w2*u67.y;
    uv2 = w0*u23.x + w1*u45.y + w2*u8c.x;
    n0  = w0*m01.x + w1*m23.y + w2*m67.x;
    n1  = w0*m01.y + w1*m45.x + w2*m67.y;
    n2  = w0*m23.x + w1*m45.y + w2*u8c.y;
    float tnz = w0*q0.x + w1*q0.y + w2*q0.z;   // fp32: hard threshold
    pm = (tnz < -0.05f) ? 1.0f : 0.0f;
}

// ---------------------------------------------------------------------------
// K4: raster, 4 consecutive pixels/thread. PLAIN loads for streams (L3/L2
// resident across replays -- NT loads bypassed cache and paid full HBM
// latency); NT stores for write-once outputs (no-RFO).
// ---------------------------------------------------------------------------
__global__ __launch_bounds__(256) void raster6(const i4* __restrict__ p2f4,
                                               const f4* __restrict__ bary4,
                                               const float4* __restrict__ rec,
                                               float* __restrict__ out) {
    int t = blockIdx.x * blockDim.x + threadIdx.x;
    const int NQ = BB_ * HH_ * HH_ / 4;
    if (t >= NQ) return;
    int pix0 = t << 2;
    int b    = pix0 >> 18;               // H*H = 2^18
    int yx0  = pix0 & (HH_*HH_ - 1);

    i4 pf = p2f4[t];
    f4 B0 = bary4[(long long)t*3 + 0];
    f4 B1 = bary4[(long long)t*3 + 1];
    f4 B2 = bary4[(long long)t*3 + 2];

    float uv0a, uv1a, uv2a, n0a, n1a, n2a, pma;
    float uv0b, uv1b, uv2b, n0b, n1b, n2b, pmb;
    float uv0c, uv1c, uv2c, n0c, n1c, n2c, pmc;
    float uv0d, uv1d, uv2d, n0d, n1d, n2d, pmd;

    shade(pf.x, B0.x, B0.y, B0.z, rec, uv0a, uv1a, uv2a, n0a, n1a, n2a, pma);
    shade(pf.y, B0.w, B1.x, B1.y, rec, uv0b, uv1b, uv2b, n0b, n1b, n2b, pmb);
    shade(pf.z, B1.z, B1.w, B2.x, rec, uv0c, uv1c, uv2c, n0c, n1c, n2c, pmc);
    shade(pf.w, B2.y, B2.z, B2.w, rec, uv0d, uv1d, uv2d, n0d, n1d, n2d, pmd);

    const long long HW = (long long)HH_ * HH_;
    f4 vuv0 = {uv0a, uv0b, uv0c, uv0d};
    f4 vuv1 = {uv1a, uv1b, uv1c, uv1d};
    f4 vuv2 = {uv2a, uv2b, uv2c, uv2d};
    f4 vpos = {pma,  pmb,  pmc,  pmd};
    f4 vg0  = {uv0a, uv1a, uv0b, uv1b};
    f4 vg1  = {uv0c, uv1c, uv0d, uv1d};
    f4 vn0  = {n0a, n0b, n0c, n0d};
    f4 vn1  = {n1a, n1b, n1c, n1d};
    f4 vn2  = {n2a, n2b, n2c, n2d};

    __builtin_nontemporal_store(vuv0, (f4*)(out + OUT_UV  + ((long long)(b*3+0))*HW + yx0));
    __builtin_nontemporal_store(vuv1, (f4*)(out + OUT_UV  + ((long long)(b*3+1))*HW + yx0));
    __builtin_nontemporal_store(vuv2, (f4*)(out + OUT_UV  + ((long long)(b*3+2))*HW + yx0));
    __builtin_nontemporal_store(vpos, (f4*)(out + OUT_POS + (long long)b*HW + yx0));
    float* gbase = out + OUT_GRID + ((long long)b*HW + yx0)*2;
    __builtin_nontemporal_store(vg0, (f4*)(gbase + 0));
    __builtin_nontemporal_store(vg1, (f4*)(gbase + 4));
    __builtin_nontemporal_store(vn0, (f4*)(out + OUT_NIMG + ((long long)(b*3+0))*HW + yx0));
    __builtin_nontemporal_store(vn1, (f4*)(out + OUT_NIMG + ((long long)(b*3+1))*HW + yx0));
    __builtin_nontemporal_store(vn2, (f4*)(out + OUT_NIMG + ((long long)(b*3+2))*HW + yx0));
}

extern "C" void kernel_launch(void* const* d_in, const int* in_sizes, int n_in,
                              void* d_out, int out_size, void* d_ws, size_t ws_size,
                              hipStream_t stream) {
    const float* vertices  = (const float*)d_in[0];
    const float* tvertices = (const float*)d_in[1];
    const float* face_uvc  = (const float*)d_in[3];
    const float* bary      = (const float*)d_in[4];
    const int*   faces     = (const int*)d_in[5];
    const int*   p2f       = (const int*)d_in[6];

    float* out = (float*)d_out;

    // ws layout (16B-aligned first): rec | fnorm | nbuf | cnt | adj
    float4* rec   = (float4*)d_ws;                               // B*F*4 float4
    float4* fnorm = rec + (size_t)BB_ * FF_ * 4;                 // B*2*F float4
    float4* nbuf  = fnorm + (size_t)BB_ * 2 * FF_;               // B*V float4
    int*    cnt   = (int*)(nbuf + (size_t)BB_ * VV_);            // V
    int*    adj   = cnt + VV_;                                   // V*K_ADJ

    hipMemsetAsync(cnt, 0, (size_t)VV_ * sizeof(int), stream);

    {
        int n = BB_ * 2 * FF_;
        facenorm3_k<<<(n + 63) / 64, 64, 0, stream>>>(vertices, tvertices, faces,
                                                      fnorm, cnt, adj);
    }
    {
        int n = BB_ * 2 * VV_;
        gather3_k<<<(n + 63) / 64, 64, 0, stream>>>(cnt, adj, fnorm,
                                                    out + OUT_N, out + OUT_TN, nbuf);
    }
    {
        int n = BB_ * FF_;
        build_rec64<<<(n + 63) / 64, 64, 0, stream>>>(faces, face_uvc, nbuf, rec);
    }
    {
        int nq = BB_ * HH_ * HH_ / 4;
        raster6<<<(nq + 255) / 256, 256, 0, stream>>>((const i4*)p2f, (const f4*)bary,
                                                      rec, out);
    }
}